// Round 9
// baseline (324.524 us; speedup 1.0000x reference)
//
#include <hip/hip_runtime.h>

#define NF 768
#define D1 10
#define D2 128
#define BM 64

typedef __attribute__((ext_vector_type(8))) short bf16x8;
typedef __attribute__((ext_vector_type(16))) float f32x16;

static __device__ __forceinline__ float sigf(float v){ return 1.0f/(1.0f+__expf(-v)); }
static __device__ __forceinline__ float tanhfast(float v){ return 2.0f/(1.0f+__expf(-2.0f*v)) - 1.0f; }
static __device__ __forceinline__ short f2bf(float f){
    unsigned u = __float_as_uint(f);
    u += 0x7fffu + ((u>>16)&1u);
    return (short)(u>>16);
}

// async global->LDS, 16B per lane, LDS dest = wave-uniform base + lane*16
static __device__ __forceinline__ void gload16(const void* g, void* l){
    __builtin_amdgcn_global_load_lds(
        (const __attribute__((address_space(1))) unsigned int*)(unsigned long long)g,
        (__attribute__((address_space(3))) unsigned int*)(unsigned long long)l,
        16, 0, 0);
}

static __device__ __forceinline__ bf16x8 cvt8(float4 a, float4 b){
    unsigned u0,u1,u2,u3;
    asm("v_cvt_pk_bf16_f32 %0, %1, %2" : "=v"(u0) : "v"(a.x), "v"(a.y));
    asm("v_cvt_pk_bf16_f32 %0, %1, %2" : "=v"(u1) : "v"(a.z), "v"(a.w));
    asm("v_cvt_pk_bf16_f32 %0, %1, %2" : "=v"(u2) : "v"(b.x), "v"(b.y));
    asm("v_cvt_pk_bf16_f32 %0, %1, %2" : "=v"(u3) : "v"(b.z), "v"(b.w));
    union { unsigned u[4]; bf16x8 v; } r;
    r.u[0]=u0; r.u[1]=u1; r.u[2]=u2; r.u[3]=u3;
    return r.v;
}

// ---- degree counts ----
__global__ void k_deg(const int* __restrict__ dst, int* __restrict__ cnt, int E){
    int e = blockIdx.x*256 + threadIdx.x;
    if(e<E) atomicAdd(&cnt[dst[e]], 1);
}

// ---- scan (rowptr/rowcur) + dinv fused, single block ----
__global__ __launch_bounds__(256) void k_scan(const int* __restrict__ cnt,
                                              int* __restrict__ rowptr, int* __restrict__ rowcur,
                                              float* __restrict__ dinv, int N, int E){
    __shared__ int part[256];
    int t = threadIdx.x;
    int C = (N+255)/256;
    int lo = t*C, hi = lo+C; if(hi>N) hi=N; if(lo>N) lo=N;
    int s=0;
    for(int i=lo;i<hi;i++) s += cnt[i];
    part[t]=s;
    __syncthreads();
    if(t==0){
        int run=0;
        for(int i=0;i<256;i++){ int v=part[i]; part[i]=run; run+=v; }
        rowptr[N]=E;
    }
    __syncthreads();
    int run = part[t];
    for(int i=lo;i<hi;i++){
        rowptr[i]=run; rowcur[i]=run; run += cnt[i];
        dinv[i] = rsqrtf((float)cnt[i] + 1.0f);
    }
}

__global__ void k_fill(const int* __restrict__ src, const int* __restrict__ dst,
                       const float* __restrict__ dinv, int* __restrict__ rowcur,
                       int* __restrict__ esrc, float* __restrict__ enorm, int E){
    int e = blockIdx.x*256 + threadIdx.x;
    if(e>=E) return;
    int s=src[e], d=dst[e];
    int pos = atomicAdd(&rowcur[d], 1);
    esrc[pos]=s;
    enorm[pos]=dinv[s]*dinv[d];
}

// ---- h1 = x @ W1 ----
__global__ __launch_bounds__(256) void k_h1(const float* __restrict__ x,
                                            const float* __restrict__ W1,
                                            float* __restrict__ h1, int N){
    __shared__ float wt[D1*NF];
    for(int idx=threadIdx.x; idx<NF*D1; idx+=256){
        int k=idx/D1, c=idx-k*D1;
        wt[c*NF+k]=W1[idx];
    }
    __syncthreads();
    int row = blockIdx.x*4 + (threadIdx.x>>6);
    int lane = threadIdx.x&63;
    if(row>=N) return;
    const float4* xr = (const float4*)(x + (size_t)row*NF);
    float acc[D1];
#pragma unroll
    for(int c=0;c<D1;c++) acc[c]=0.f;
#pragma unroll
    for(int i=0;i<3;i++){
        float4 v = xr[lane + 64*i];
#pragma unroll
        for(int c=0;c<D1;c++){
            float4 w = *(const float4*)&wt[c*NF + (lane+64*i)*4];
            acc[c] += v.x*w.x + v.y*w.y + v.z*w.z + v.w*w.w;
        }
    }
#pragma unroll
    for(int c=0;c<D1;c++){
        float v=acc[c];
#pragma unroll
        for(int off=32;off;off>>=1) v += __shfl_down(v,off,64);
        acc[c]=v;
    }
    if(lane==0){
#pragma unroll
        for(int c=0;c<D1;c++) h1[(size_t)row*D1+c]=acc[c];
    }
}

// ---- layer-1 CSR gather + relu ----
__global__ __launch_bounds__(256) void k_gath1(const float* __restrict__ h1,
        const int* __restrict__ rowptr, const int* __restrict__ esrc,
        const float* __restrict__ enorm, const float* __restrict__ dinv,
        const float* __restrict__ b1, float* __restrict__ h, int N){
    int node = blockIdx.x*4 + (threadIdx.x>>6);
    int lane = threadIdx.x&63;
    if(node>=N) return;
    int e0=rowptr[node], e1=rowptr[node+1];
    float acc[D1];
#pragma unroll
    for(int c=0;c<D1;c++) acc[c]=0.f;
    for(int e=e0+lane; e<e1; e+=64){
        int s=esrc[e]; float w=enorm[e];
        const float* hr = h1 + (size_t)s*D1;
#pragma unroll
        for(int c=0;c<D1;c++) acc[c] += hr[c]*w;
    }
    if(lane==0){
        float di=dinv[node], d2=di*di;
        const float* hr = h1 + (size_t)node*D1;
#pragma unroll
        for(int c=0;c<D1;c++) acc[c] += hr[c]*d2;
    }
#pragma unroll
    for(int c=0;c<D1;c++){
        float v=acc[c];
#pragma unroll
        for(int off=32;off;off>>=1) v += __shfl_down(v,off,64);
        acc[c]=v;
    }
    if(lane==0){
#pragma unroll
        for(int c=0;c<D1;c++){
            float v = acc[c] + b1[c];
            h[(size_t)node*D1+c] = v>0.f ? v : 0.f;
        }
    }
}

__global__ __launch_bounds__(128) void k_hz(const float* __restrict__ h,
                                            const float* __restrict__ W2,
                                            float* __restrict__ hz, int N){
    __shared__ float w2s[D1*D2];
    int j = threadIdx.x;
    for(int i=j;i<D1*D2;i+=128) w2s[i]=W2[i];
    __syncthreads();
    int n = blockIdx.x;
    if(n>=N) return;
    const float* hr = h + (size_t)n*D1;
    float acc=0.f;
#pragma unroll
    for(int k=0;k<D1;k++) acc += hr[k]*w2s[k*D2+j];
    hz[(size_t)n*D2+j]=acc;
}

// ---- layer-2 CSR gather (fused zfin), writes fp32 z table ----
__global__ __launch_bounds__(128) void k_gath2(const float* __restrict__ hz,
        const int* __restrict__ rowptr, const int* __restrict__ esrc,
        const float* __restrict__ enorm, const float* __restrict__ dinv,
        const float* __restrict__ b2, float* __restrict__ zbf, int N){
    int n = blockIdx.x;
    int c = threadIdx.x;
    int e0 = rowptr[n], e1 = rowptr[n+1];
    float di = dinv[n];
    float acc = hz[(size_t)n*D2+c]*di*di + b2[c];
    int e = e0;
    for(; e+1<e1; e+=2){
        int s0=esrc[e], s1=esrc[e+1];
        float w0=enorm[e], w1=enorm[e+1];
        acc += hz[(size_t)s0*D2+c]*w0 + hz[(size_t)s1*D2+c]*w1;
    }
    if(e<e1) acc += hz[(size_t)esrc[e]*D2+c]*enorm[e];
    zbf[(size_t)n*D2+c] = acc;
}

// ---- B fragment image over FULL K=1024: 12 frags x 64 ks16 x 64 lanes x 8 bf16 ----
__global__ void k_wimgB(const float* __restrict__ Wih, ushort* __restrict__ img){
    int gid = blockIdx.x*256 + threadIdx.x;        // 12*64*64 = 49152
    if(gid >= 12*64*64) return;
    int l = gid & 63;
    int ks16 = (gid>>6) & 63;
    int f = gid >> 12;
    int dd = l & 31, kb = l>>5;
    int wn = f/3, gi = f - wn*3;
    int gbase = (gi==0)?0:((gi==1)?256:384);
    int wrow = gbase + wn*32 + dd;
    int k = ks16*16 + kb*8;
    const float* p = Wih + (size_t)wrow*1024 + k;
    float4 v0=*(const float4*)p, v1=*(const float4*)(p+4);
    bf16x8 o;
    o[0]=f2bf(v0.x); o[1]=f2bf(v0.y); o[2]=f2bf(v0.z); o[3]=f2bf(v0.w);
    o[4]=f2bf(v1.x); o[5]=f2bf(v1.y); o[6]=f2bf(v1.z); o[7]=f2bf(v1.w);
    *(bf16x8*)(img + (size_t)gid*8) = o;
}

// ---- fused MFMA GEMM + LSTM. K=1024 feat = [z_h|r_emb|z_t], BK=32, 32 chunks.
// BOTH A (HBM, fp32) and B (L2 image, bf16) staged via global_load_lds in one
// program-ordered stream: A ring depth 4, B ring depth 2, counted vmcnt(2)
// per chunk — A has a 3-chunk lead, queue never drains mid-loop. No register
// VMEM in the loop => no compiler vmcnt interference, no spills. ----
__global__ __launch_bounds__(256,2) void k_big(
    const float* __restrict__ remb, const ushort* __restrict__ img,
    const float* __restrict__ zbf, const float* __restrict__ b_ih,
    const float* __restrict__ b_hh, const int* __restrict__ trip,
    float* __restrict__ score, int T)
{
    __shared__ float  Ar[4][64*32];      // 4 x 8 KB   fp32 A chunks (swizzled)
    __shared__ ushort Br[2][24*64*8];    // 2 x 24 KB  B: 12 frags x 2 ks16
    int tid=threadIdx.x, lane=tid&63, w=tid>>6;
    int l31=lane&31, lh=lane>>5;
    int t0=blockIdx.x*BM;

    // A staging: wave w stages rows [w*16, w*16+16) as 2 slices of 8 rows.
    // lane: row-in-slice = lane>>3, 16B slot = lane&7; source pre-swizzled.
    const int arow = lane>>3;
    const int lsl  = ((lane&7) ^ arow)*4;      // swizzled source offset (floats)
    int tcA[2], thA[2], ttA[2];
#pragma unroll
    for(int j=0;j<2;j++){
        int row = w*16 + j*8 + arow;
        int tc = t0+row; if(tc>=T) tc=T-1;
        tcA[j]=tc; thA[j]=trip[3*tc]; ttA[j]=trip[3*tc+2];
    }
    const int rx = l31&7;                      // read-side XOR (row&7)

    f32x16 acc[2][3];
    const f32x16 zer = {0,0,0,0,0,0,0,0,0,0,0,0,0,0,0,0};
#pragma unroll
    for(int m=0;m<2;m++)
#pragma unroll
        for(int g=0;g<3;g++) acc[m][g]=zer;

#define AISSUE(C_) if((C_)<32){ \
    _Pragma("unroll") \
    for(int j_=0;j_<2;j_++){ \
        const float* s_; \
        if((C_)<4)       s_ = zbf + (size_t)thA[j_]*D2 + (C_)*32 + lsl; \
        else if((C_)<28) s_ = remb + (size_t)tcA[j_]*NF + ((C_)-4)*32 + lsl; \
        else             s_ = zbf + (size_t)ttA[j_]*D2 + ((C_)-28)*32 + lsl; \
        gload16(s_, &Ar[(C_)&3][(w*16 + j_*8)*32]); \
    } }

#define BISSUE(C_) if((C_)<32){ \
    _Pragma("unroll") \
    for(int j_=0;j_<6;j_++){ \
        const int i_ = w*6+j_, f_ = i_>>1, s_ = i_&1; \
        gload16(img + ((size_t)(f_*64 + (C_)*2 + s_)*64 + lane)*8, \
                &Br[(C_)&1][(f_*2+s_)*64*8]); \
    } }

#define KSTEP(C_,S_) { \
    const float* ar_ = &Ar[(C_)&3][0]; \
    const ushort* br_ = &Br[(C_)&1][0]; \
    const int q0_ = (S_)*4 + lh*2; \
    float4 a00_ = *(const float4*)&ar_[ l31*32      + ((q0_  )^rx)*4 ]; \
    float4 a01_ = *(const float4*)&ar_[ l31*32      + ((q0_+1)^rx)*4 ]; \
    bf16x8 A0_ = cvt8(a00_,a01_); \
    float4 a10_ = *(const float4*)&ar_[ (32+l31)*32 + ((q0_  )^rx)*4 ]; \
    float4 a11_ = *(const float4*)&ar_[ (32+l31)*32 + ((q0_+1)^rx)*4 ]; \
    bf16x8 A1_ = cvt8(a10_,a11_); \
    bf16x8 B0_ = *(const bf16x8*)&br_[(((w*3+0)*2+(S_))*64 + lane)*8]; \
    bf16x8 B1_ = *(const bf16x8*)&br_[(((w*3+1)*2+(S_))*64 + lane)*8]; \
    bf16x8 B2_ = *(const bf16x8*)&br_[(((w*3+2)*2+(S_))*64 + lane)*8]; \
    acc[0][0]=__builtin_amdgcn_mfma_f32_32x32x16_bf16(A0_,B0_,acc[0][0],0,0,0); \
    acc[0][1]=__builtin_amdgcn_mfma_f32_32x32x16_bf16(A0_,B1_,acc[0][1],0,0,0); \
    acc[0][2]=__builtin_amdgcn_mfma_f32_32x32x16_bf16(A0_,B2_,acc[0][2],0,0,0); \
    acc[1][0]=__builtin_amdgcn_mfma_f32_32x32x16_bf16(A1_,B0_,acc[1][0],0,0,0); \
    acc[1][1]=__builtin_amdgcn_mfma_f32_32x32x16_bf16(A1_,B1_,acc[1][1],0,0,0); \
    acc[1][2]=__builtin_amdgcn_mfma_f32_32x32x16_bf16(A1_,B2_,acc[1][2],0,0,0); \
}

// per chunk: wait A(C),B(C) [exactly 2 newer ops outstanding in steady state],
// barrier, issue B(C+1) then A(C+3), compute 2 ks16.
#define CHUNK(C_,W_) { \
    asm volatile("s_waitcnt vmcnt(" W_ ")" ::: "memory"); \
    __builtin_amdgcn_s_barrier(); \
    __builtin_amdgcn_sched_barrier(0); \
    BISSUE((C_)+1) \
    AISSUE((C_)+3) \
    __builtin_amdgcn_sched_barrier(0); \
    __builtin_amdgcn_s_setprio(1); \
    KSTEP(C_,0) KSTEP(C_,1) \
    __builtin_amdgcn_s_setprio(0); \
}

    // prologue: A0, A1, B0, A2  (order => wait vmcnt(2) at chunk 0 is exact)
    AISSUE(0) AISSUE(1) BISSUE(0) AISSUE(2)
    __builtin_amdgcn_sched_barrier(0);

    CHUNK(0 ,"2") CHUNK(1 ,"2") CHUNK(2 ,"2") CHUNK(3 ,"2")
    CHUNK(4 ,"2") CHUNK(5 ,"2") CHUNK(6 ,"2") CHUNK(7 ,"2")
    CHUNK(8 ,"2") CHUNK(9 ,"2") CHUNK(10,"2") CHUNK(11,"2")
    CHUNK(12,"2") CHUNK(13,"2") CHUNK(14,"2") CHUNK(15,"2")
    CHUNK(16,"2") CHUNK(17,"2") CHUNK(18,"2") CHUNK(19,"2")
    CHUNK(20,"2") CHUNK(21,"2") CHUNK(22,"2") CHUNK(23,"2")
    CHUNK(24,"2") CHUNK(25,"2") CHUNK(26,"2") CHUNK(27,"2")
    CHUNK(28,"2") CHUNK(29,"2") CHUNK(30,"0") CHUNK(31,"0")
#undef CHUNK
#undef KSTEP
#undef BISSUE
#undef AISSUE

    // ---- epilogue: bias + LSTM + row-sum reduce (reuse Ar[0] as rowsum) ----
    float* rowsum = &Ar[0][0];
    __syncthreads();
    if(tid<BM) rowsum[tid]=0.f;
    __syncthreads();
    int d = w*32+l31;
    float bi=b_ih[d]+b_hh[d];
    float bg=b_ih[256+d]+b_hh[256+d];
    float bo=b_ih[384+d]+b_hh[384+d];
#pragma unroll
    for(int m=0;m<2;m++){
#pragma unroll
        for(int r=0;r<16;r++){
            int row = m*32 + (r&3)+8*(r>>2)+4*lh;
            float ig = acc[m][0][r] + bi;
            float gg = acc[m][1][r] + bg;
            float og = acc[m][2][r] + bo;
            float cc = sigf(ig)*tanhfast(gg);
            float ov = sigf(og)*tanhfast(cc);
#pragma unroll
            for(int off=1; off<32; off<<=1) ov += __shfl_xor(ov, off, 64);
            if(l31==0) atomicAdd(&rowsum[row], ov);
        }
    }
    __syncthreads();
    if(tid < BM){
        int t = t0 + tid;
        if(t < T) score[t] = sigf(rowsum[tid]);
    }
}

extern "C" void kernel_launch(void* const* d_in, const int* in_sizes, int n_in,
                              void* d_out, int out_size, void* d_ws, size_t ws_size,
                              hipStream_t stream){
    const float* x    = (const float*)d_in[0];
    const float* remb = (const float*)d_in[1];
    const float* W1   = (const float*)d_in[2];
    const float* b1   = (const float*)d_in[3];
    const float* W2   = (const float*)d_in[4];
    const float* b2   = (const float*)d_in[5];
    const float* Wih  = (const float*)d_in[6];
    const float* b_ih = (const float*)d_in[8];
    const float* b_hh = (const float*)d_in[9];
    const int*   ei   = (const int*)d_in[10];
    const int*   trip = (const int*)d_in[11];
    float* score = (float*)d_out;

    const int N = in_sizes[0]/NF;       // 15000
    const int E = in_sizes[10]/2;       // 200000
    const int T = in_sizes[11]/3;       // 100000
    const int* src = ei;
    const int* dst = ei + E;

    float* ws = (float*)d_ws;
    size_t o = 0;
    ushort* img  = (ushort*)(ws+o); o += (size_t)12*64*64*8/2;   // 786 KB
    float* zbf   = ws+o;            o += (size_t)N*D2;           // fp32 z, 7.7 MB
    int*   cnt    = (int*)(ws+o);   o += (size_t)((N+8)&~7);
    int*   rowptr = (int*)(ws+o);   o += (size_t)((N+8)&~7);
    int*   rowcur = (int*)(ws+o);   o += (size_t)((N+8)&~7);
    int*   esrc   = (int*)(ws+o);   o += (size_t)E;
    float* enorm  = ws+o;           o += (size_t)E;
    float* dinv   = ws+o;           o += (size_t)((N+7)&~7);
    float* h1     = ws+o;           o += (size_t)N*D1;
    float* hbuf   = ws+o;           o += (size_t)N*D1;
    float* hz     = ws+o;           o += (size_t)N*D2;
    (void)ws_size; (void)n_in; (void)out_size;

    hipMemsetAsync(cnt, 0, (size_t)N*sizeof(int), stream);

    k_wimgB<<<dim3((12*64*64+255)/256), dim3(256), 0, stream>>>(Wih, img);
    k_deg  <<<dim3((E+255)/256), dim3(256), 0, stream>>>(dst, cnt, E);
    k_scan <<<dim3(1), dim3(256), 0, stream>>>(cnt, rowptr, rowcur, dinv, N, E);
    k_fill <<<dim3((E+255)/256), dim3(256), 0, stream>>>(src, dst, dinv, rowcur, esrc, enorm, E);
    k_h1   <<<dim3((N+3)/4), dim3(256), 0, stream>>>(x, W1, h1, N);
    k_gath1<<<dim3((N+3)/4), dim3(256), 0, stream>>>(h1, rowptr, esrc, enorm, dinv, b1, hbuf, N);
    k_hz   <<<dim3(N), dim3(128), 0, stream>>>(hbuf, W2, hz, N);
    k_gath2<<<dim3(N), dim3(128), 0, stream>>>(hz, rowptr, esrc, enorm, dinv, b2, zbf, N);
    k_big  <<<dim3((T+BM-1)/BM), dim3(256), 0, stream>>>(remb, img, zbf, b_ih, b_hh, trip, score, T);
}

// Round 10
// 302.163 us; speedup vs baseline: 1.0740x; 1.0740x over previous
//
#include <hip/hip_runtime.h>

#define NF 768
#define D1 10
#define D2 128
#define BM 64

typedef __attribute__((ext_vector_type(8))) short bf16x8;
typedef __attribute__((ext_vector_type(16))) float f32x16;

static __device__ __forceinline__ float sigf(float v){ return 1.0f/(1.0f+__expf(-v)); }
static __device__ __forceinline__ float tanhfast(float v){ return 2.0f/(1.0f+__expf(-2.0f*v)) - 1.0f; }
static __device__ __forceinline__ short f2bf(float f){
    unsigned u = __float_as_uint(f);
    u += 0x7fffu + ((u>>16)&1u);
    return (short)(u>>16);
}

// async global->LDS, 16B per lane, LDS dest = wave-uniform base + lane*16
static __device__ __forceinline__ void gload16(const void* g, void* l){
    __builtin_amdgcn_global_load_lds(
        (const __attribute__((address_space(1))) unsigned int*)(unsigned long long)g,
        (__attribute__((address_space(3))) unsigned int*)(unsigned long long)l,
        16, 0, 0);
}

static __device__ __forceinline__ short4 cvt4(float4 a){
    unsigned u0,u1;
    asm("v_cvt_pk_bf16_f32 %0, %1, %2" : "=v"(u0) : "v"(a.x), "v"(a.y));
    asm("v_cvt_pk_bf16_f32 %0, %1, %2" : "=v"(u1) : "v"(a.z), "v"(a.w));
    union { unsigned u[2]; short4 s; } r;
    r.u[0]=u0; r.u[1]=u1;
    return r.s;
}

// ---- degree counts ----
__global__ void k_deg(const int* __restrict__ dst, int* __restrict__ cnt, int E){
    int e = blockIdx.x*256 + threadIdx.x;
    if(e<E) atomicAdd(&cnt[dst[e]], 1);
}

// ---- scan (rowptr/rowcur) + dinv fused, single block ----
__global__ __launch_bounds__(256) void k_scan(const int* __restrict__ cnt,
                                              int* __restrict__ rowptr, int* __restrict__ rowcur,
                                              float* __restrict__ dinv, int N, int E){
    __shared__ int part[256];
    int t = threadIdx.x;
    int C = (N+255)/256;
    int lo = t*C, hi = lo+C; if(hi>N) hi=N; if(lo>N) lo=N;
    int s=0;
    for(int i=lo;i<hi;i++) s += cnt[i];
    part[t]=s;
    __syncthreads();
    if(t==0){
        int run=0;
        for(int i=0;i<256;i++){ int v=part[i]; part[i]=run; run+=v; }
        rowptr[N]=E;
    }
    __syncthreads();
    int run = part[t];
    for(int i=lo;i<hi;i++){
        rowptr[i]=run; rowcur[i]=run; run += cnt[i];
        dinv[i] = rsqrtf((float)cnt[i] + 1.0f);
    }
}

__global__ void k_fill(const int* __restrict__ src, const int* __restrict__ dst,
                       const float* __restrict__ dinv, int* __restrict__ rowcur,
                       int* __restrict__ esrc, float* __restrict__ enorm, int E){
    int e = blockIdx.x*256 + threadIdx.x;
    if(e>=E) return;
    int s=src[e], d=dst[e];
    int pos = atomicAdd(&rowcur[d], 1);
    esrc[pos]=s;
    enorm[pos]=dinv[s]*dinv[d];
}

// ---- h1 = x @ W1 ----
__global__ __launch_bounds__(256) void k_h1(const float* __restrict__ x,
                                            const float* __restrict__ W1,
                                            float* __restrict__ h1, int N){
    __shared__ float wt[D1*NF];
    for(int idx=threadIdx.x; idx<NF*D1; idx+=256){
        int k=idx/D1, c=idx-k*D1;
        wt[c*NF+k]=W1[idx];
    }
    __syncthreads();
    int row = blockIdx.x*4 + (threadIdx.x>>6);
    int lane = threadIdx.x&63;
    if(row>=N) return;
    const float4* xr = (const float4*)(x + (size_t)row*NF);
    float acc[D1];
#pragma unroll
    for(int c=0;c<D1;c++) acc[c]=0.f;
#pragma unroll
    for(int i=0;i<3;i++){
        float4 v = xr[lane + 64*i];
#pragma unroll
        for(int c=0;c<D1;c++){
            float4 w = *(const float4*)&wt[c*NF + (lane+64*i)*4];
            acc[c] += v.x*w.x + v.y*w.y + v.z*w.z + v.w*w.w;
        }
    }
#pragma unroll
    for(int c=0;c<D1;c++){
        float v=acc[c];
#pragma unroll
        for(int off=32;off;off>>=1) v += __shfl_down(v,off,64);
        acc[c]=v;
    }
    if(lane==0){
#pragma unroll
        for(int c=0;c<D1;c++) h1[(size_t)row*D1+c]=acc[c];
    }
}

// ---- layer-1 CSR gather + relu ----
__global__ __launch_bounds__(256) void k_gath1(const float* __restrict__ h1,
        const int* __restrict__ rowptr, const int* __restrict__ esrc,
        const float* __restrict__ enorm, const float* __restrict__ dinv,
        const float* __restrict__ b1, float* __restrict__ h, int N){
    int node = blockIdx.x*4 + (threadIdx.x>>6);
    int lane = threadIdx.x&63;
    if(node>=N) return;
    int e0=rowptr[node], e1=rowptr[node+1];
    float acc[D1];
#pragma unroll
    for(int c=0;c<D1;c++) acc[c]=0.f;
    for(int e=e0+lane; e<e1; e+=64){
        int s=esrc[e]; float w=enorm[e];
        const float* hr = h1 + (size_t)s*D1;
#pragma unroll
        for(int c=0;c<D1;c++) acc[c] += hr[c]*w;
    }
    if(lane==0){
        float di=dinv[node], d2=di*di;
        const float* hr = h1 + (size_t)node*D1;
#pragma unroll
        for(int c=0;c<D1;c++) acc[c] += hr[c]*d2;
    }
#pragma unroll
    for(int c=0;c<D1;c++){
        float v=acc[c];
#pragma unroll
        for(int off=32;off;off>>=1) v += __shfl_down(v,off,64);
        acc[c]=v;
    }
    if(lane==0){
#pragma unroll
        for(int c=0;c<D1;c++){
            float v = acc[c] + b1[c];
            h[(size_t)node*D1+c] = v>0.f ? v : 0.f;
        }
    }
}

__global__ __launch_bounds__(128) void k_hz(const float* __restrict__ h,
                                            const float* __restrict__ W2,
                                            float* __restrict__ hz, int N){
    __shared__ float w2s[D1*D2];
    int j = threadIdx.x;
    for(int i=j;i<D1*D2;i+=128) w2s[i]=W2[i];
    __syncthreads();
    int n = blockIdx.x;
    if(n>=N) return;
    const float* hr = h + (size_t)n*D1;
    float acc=0.f;
#pragma unroll
    for(int k=0;k<D1;k++) acc += hr[k]*w2s[k*D2+j];
    hz[(size_t)n*D2+j]=acc;
}

// ---- layer-2 CSR gather (fused zfin), writes fp32 z table ----
__global__ __launch_bounds__(128) void k_gath2(const float* __restrict__ hz,
        const int* __restrict__ rowptr, const int* __restrict__ esrc,
        const float* __restrict__ enorm, const float* __restrict__ dinv,
        const float* __restrict__ b2, float* __restrict__ zbf, int N){
    int n = blockIdx.x;
    int c = threadIdx.x;
    int e0 = rowptr[n], e1 = rowptr[n+1];
    float di = dinv[n];
    float acc = hz[(size_t)n*D2+c]*di*di + b2[c];
    int e = e0;
    for(; e+1<e1; e+=2){
        int s0=esrc[e], s1=esrc[e+1];
        float w0=enorm[e], w1=enorm[e+1];
        acc += hz[(size_t)s0*D2+c]*w0 + hz[(size_t)s1*D2+c]*w1;
    }
    if(e<e1) acc += hz[(size_t)esrc[e]*D2+c]*enorm[e];
    zbf[(size_t)n*D2+c] = acc;
}

// ---- B fragment image over FULL K=1024: 12 frags x 64 ks16 x 64 lanes x 8 bf16 ----
__global__ void k_wimgB(const float* __restrict__ Wih, ushort* __restrict__ img){
    int gid = blockIdx.x*256 + threadIdx.x;        // 12*64*64 = 49152
    if(gid >= 12*64*64) return;
    int l = gid & 63;
    int ks16 = (gid>>6) & 63;
    int f = gid >> 12;
    int dd = l & 31, kb = l>>5;
    int wn = f/3, gi = f - wn*3;
    int gbase = (gi==0)?0:((gi==1)?256:384);
    int wrow = gbase + wn*32 + dd;
    int k = ks16*16 + kb*8;
    const float* p = Wih + (size_t)wrow*1024 + k;
    float4 v0=*(const float4*)p, v1=*(const float4*)(p+4);
    bf16x8 o;
    o[0]=f2bf(v0.x); o[1]=f2bf(v0.y); o[2]=f2bf(v0.z); o[3]=f2bf(v0.w);
    o[4]=f2bf(v1.x); o[5]=f2bf(v1.y); o[6]=f2bf(v1.z); o[7]=f2bf(v1.w);
    *(bf16x8*)(img + (size_t)gid*8) = o;
}

// ---- fused MFMA GEMM + LSTM. K=1024 feat=[z_h|r_emb|z_t], BK=16 (1 ks16), 64 chunks.
// A: coalesced float4 reg-loads (depth-4), cvt_pk -> bf16, swizzled 8B ds_write
//    into ring-2 LDS (2x2 KB). B: gload16 (1KB contiguous) into ring-3 LDS (36 KB).
// Counted vmcnt keeps 3 B-chunks + 4 A-loads in flight; 40 KB LDS -> 3-4 blocks/CU.
__global__ __launch_bounds__(256,3) void k_big(
    const float* __restrict__ remb, const ushort* __restrict__ img,
    const float* __restrict__ zbf, const float* __restrict__ b_ih,
    const float* __restrict__ b_hh, const int* __restrict__ trip,
    float* __restrict__ score, int T)
{
    __shared__ ushort Ab[2][64*16];      // 2 x 2 KB  bf16 A (swizzled cells)
    __shared__ ushort Br[3][12*512];     // 3 x 12 KB B (12 frags x 1 ks16)
    int tid=threadIdx.x, lane=tid&63, w=tid>>6;
    int l31=lane&31, lh=lane>>5;
    int t0=blockIdx.x*BM;

    // A staging geometry: lane -> row = w*16 + (lane>>2), sub = lane&3 (16B seg)
    const int arow = w*16 + (lane>>2);
    const int asub = lane&3;
    { } // (16 rows/wave, 4 lanes/row -> 64B coalesced runs)
    int tc = t0 + arow; if(tc>=T) tc=T-1;
    const float* pzh = zbf + (size_t)trip[3*tc]*D2   + asub*4;
    const float* prm = remb + (size_t)tc*NF          + asub*4;
    const float* pzt = zbf + (size_t)trip[3*tc+2]*D2 + asub*4;
    // swizzled LDS write offset (ushorts): row*16 + physcell*8 + (sub&1)*4
    const int awoff = arow*16 + (((asub>>1) ^ (arow&1))*8) + (asub&1)*4;
    // A frag read offsets (ushorts): row*16 + (lh ^ (row&1))*8
    const int ar0 = (l31)*16    + ((lh ^ (l31&1))*8);
    const int ar1 = (32+l31)*16 + ((lh ^ (l31&1))*8);

    f32x16 acc[2][3];
    const f32x16 zer = {0,0,0,0,0,0,0,0,0,0,0,0,0,0,0,0};
#pragma unroll
    for(int m=0;m<2;m++)
#pragma unroll
        for(int g=0;g<3;g++) acc[m][g]=zer;

    float4 pa[4];

#define ALOAD(C_) if((C_)<64){ \
    const float* s_; \
    if((C_)<8)       s_ = pzh + (C_)*16; \
    else if((C_)<56) s_ = prm + ((C_)-8)*16; \
    else             s_ = pzt + ((C_)-56)*16; \
    pa[(C_)&3] = *(const float4*)s_; }

#define AWRITE(C_) if((C_)<64){ \
    *(short4*)&Ab[(C_)&1][awoff] = cvt4(pa[(C_)&3]); }

#define BISSUE(C_) if((C_)<64){ \
    _Pragma("unroll") \
    for(int j_=0;j_<3;j_++){ \
        gload16(img + ((size_t)((w*3+j_)*64 + (C_))*64 + lane)*8, \
                &Br[(C_)%3][(w*3+j_)*512]); \
    } }

#define CH(C_,W_) { \
    asm volatile("s_waitcnt vmcnt(" W_ ")" ::: "memory"); \
    __builtin_amdgcn_sched_barrier(0); \
    asm volatile("s_waitcnt lgkmcnt(0)" ::: "memory"); \
    __builtin_amdgcn_s_barrier(); \
    __builtin_amdgcn_sched_barrier(0); \
    BISSUE((C_)+2) \
    __builtin_amdgcn_sched_barrier(0); \
    ALOAD((C_)+4) \
    __builtin_amdgcn_sched_barrier(0); \
    { \
        const ushort* a_ = &Ab[(C_)&1][0]; \
        const ushort* b_ = &Br[(C_)%3][0]; \
        bf16x8 A0_ = *(const bf16x8*)&a_[ar0]; \
        bf16x8 A1_ = *(const bf16x8*)&a_[ar1]; \
        bf16x8 B0_ = *(const bf16x8*)&b_[((w*3+0)*64+lane)*8]; \
        bf16x8 B1_ = *(const bf16x8*)&b_[((w*3+1)*64+lane)*8]; \
        bf16x8 B2_ = *(const bf16x8*)&b_[((w*3+2)*64+lane)*8]; \
        __builtin_amdgcn_s_setprio(1); \
        acc[0][0]=__builtin_amdgcn_mfma_f32_32x32x16_bf16(A0_,B0_,acc[0][0],0,0,0); \
        acc[0][1]=__builtin_amdgcn_mfma_f32_32x32x16_bf16(A0_,B1_,acc[0][1],0,0,0); \
        acc[0][2]=__builtin_amdgcn_mfma_f32_32x32x16_bf16(A0_,B2_,acc[0][2],0,0,0); \
        acc[1][0]=__builtin_amdgcn_mfma_f32_32x32x16_bf16(A1_,B0_,acc[1][0],0,0,0); \
        acc[1][1]=__builtin_amdgcn_mfma_f32_32x32x16_bf16(A1_,B1_,acc[1][1],0,0,0); \
        acc[1][2]=__builtin_amdgcn_mfma_f32_32x32x16_bf16(A1_,B2_,acc[1][2],0,0,0); \
        __builtin_amdgcn_s_setprio(0); \
    } \
    AWRITE((C_)+1) \
}

    // prologue: A(0..3) regs, B(0), B(1); write A(0)
    ALOAD(0) ALOAD(1) ALOAD(2) ALOAD(3)
    __builtin_amdgcn_sched_barrier(0);
    BISSUE(0) BISSUE(1)
    __builtin_amdgcn_sched_barrier(0);
    AWRITE(0)

    CH(0 ,"3") CH(1 ,"4") CH(2 ,"5") CH(3 ,"5") CH(4 ,"5") CH(5 ,"5") CH(6 ,"5") CH(7 ,"5")
    CH(8 ,"5") CH(9 ,"5") CH(10,"5") CH(11,"5") CH(12,"5") CH(13,"5") CH(14,"5") CH(15,"5")
    CH(16,"5") CH(17,"5") CH(18,"5") CH(19,"5") CH(20,"5") CH(21,"5") CH(22,"5") CH(23,"5")
    CH(24,"5") CH(25,"5") CH(26,"5") CH(27,"5") CH(28,"5") CH(29,"5") CH(30,"5") CH(31,"5")
    CH(32,"5") CH(33,"5") CH(34,"5") CH(35,"5") CH(36,"5") CH(37,"5") CH(38,"5") CH(39,"5")
    CH(40,"5") CH(41,"5") CH(42,"5") CH(43,"5") CH(44,"5") CH(45,"5") CH(46,"5") CH(47,"5")
    CH(48,"5") CH(49,"5") CH(50,"5") CH(51,"5") CH(52,"5") CH(53,"5") CH(54,"5") CH(55,"5")
    CH(56,"5") CH(57,"5") CH(58,"5") CH(59,"5") CH(60,"5") CH(61,"4") CH(62,"3") CH(63,"0")
#undef CH
#undef BISSUE
#undef AWRITE
#undef ALOAD

    // ---- epilogue: bias + LSTM + row-sum reduce (reuse Br as rowsum) ----
    float* rowsum = (float*)&Br[0][0];
    __syncthreads();
    if(tid<BM) rowsum[tid]=0.f;
    __syncthreads();
    int d = w*32+l31;
    float bi=b_ih[d]+b_hh[d];
    float bg=b_ih[256+d]+b_hh[256+d];
    float bo=b_ih[384+d]+b_hh[384+d];
#pragma unroll
    for(int m=0;m<2;m++){
#pragma unroll
        for(int r=0;r<16;r++){
            int row = m*32 + (r&3)+8*(r>>2)+4*lh;
            float ig = acc[m][0][r] + bi;
            float gg = acc[m][1][r] + bg;
            float og = acc[m][2][r] + bo;
            float cc = sigf(ig)*tanhfast(gg);
            float ov = sigf(og)*tanhfast(cc);
#pragma unroll
            for(int off=1; off<32; off<<=1) ov += __shfl_xor(ov, off, 64);
            if(l31==0) atomicAdd(&rowsum[row], ov);
        }
    }
    __syncthreads();
    if(tid < BM){
        int t = t0 + tid;
        if(t < T) score[t] = sigf(rowsum[tid]);
    }
}

extern "C" void kernel_launch(void* const* d_in, const int* in_sizes, int n_in,
                              void* d_out, int out_size, void* d_ws, size_t ws_size,
                              hipStream_t stream){
    const float* x    = (const float*)d_in[0];
    const float* remb = (const float*)d_in[1];
    const float* W1   = (const float*)d_in[2];
    const float* b1   = (const float*)d_in[3];
    const float* W2   = (const float*)d_in[4];
    const float* b2   = (const float*)d_in[5];
    const float* Wih  = (const float*)d_in[6];
    const float* b_ih = (const float*)d_in[8];
    const float* b_hh = (const float*)d_in[9];
    const int*   ei   = (const int*)d_in[10];
    const int*   trip = (const int*)d_in[11];
    float* score = (float*)d_out;

    const int N = in_sizes[0]/NF;       // 15000
    const int E = in_sizes[10]/2;       // 200000
    const int T = in_sizes[11]/3;       // 100000
    const int* src = ei;
    const int* dst = ei + E;

    float* ws = (float*)d_ws;
    size_t o = 0;
    ushort* img  = (ushort*)(ws+o); o += (size_t)12*64*64*8/2;   // 786 KB
    float* zbf   = ws+o;            o += (size_t)N*D2;           // fp32 z, 7.7 MB
    int*   cnt    = (int*)(ws+o);   o += (size_t)((N+8)&~7);
    int*   rowptr = (int*)(ws+o);   o += (size_t)((N+8)&~7);
    int*   rowcur = (int*)(ws+o);   o += (size_t)((N+8)&~7);
    int*   esrc   = (int*)(ws+o);   o += (size_t)E;
    float* enorm  = ws+o;           o += (size_t)E;
    float* dinv   = ws+o;           o += (size_t)((N+7)&~7);
    float* h1     = ws+o;           o += (size_t)N*D1;
    float* hbuf   = ws+o;           o += (size_t)N*D1;
    float* hz     = ws+o;           o += (size_t)N*D2;
    (void)ws_size; (void)n_in; (void)out_size;

    hipMemsetAsync(cnt, 0, (size_t)N*sizeof(int), stream);

    k_wimgB<<<dim3((12*64*64+255)/256), dim3(256), 0, stream>>>(Wih, img);
    k_deg  <<<dim3((E+255)/256), dim3(256), 0, stream>>>(dst, cnt, E);
    k_scan <<<dim3(1), dim3(256), 0, stream>>>(cnt, rowptr, rowcur, dinv, N, E);
    k_fill <<<dim3((E+255)/256), dim3(256), 0, stream>>>(src, dst, dinv, rowcur, esrc, enorm, E);
    k_h1   <<<dim3((N+3)/4), dim3(256), 0, stream>>>(x, W1, h1, N);
    k_gath1<<<dim3((N+3)/4), dim3(256), 0, stream>>>(h1, rowptr, esrc, enorm, dinv, b1, hbuf, N);
    k_hz   <<<dim3(N), dim3(128), 0, stream>>>(hbuf, W2, hz, N);
    k_gath2<<<dim3(N), dim3(128), 0, stream>>>(hz, rowptr, esrc, enorm, dinv, b2, zbf, N);
    k_big  <<<dim3((T+BM-1)/BM), dim3(256), 0, stream>>>(remb, img, zbf, b_ih, b_hh, trip, score, T);
}